// Round 9
// baseline (708.845 us; speedup 1.0000x reference)
//
#include <hip/hip_runtime.h>
#include <cstdint>
#include <cstddef>

#define FEAT 512
#define HID 256
#define CLS 40
#define EPS 1e-5f

typedef __attribute__((ext_vector_type(8))) short short8;
typedef __attribute__((ext_vector_type(4))) float f32x4v;

// ---------------- helpers ----------------

__device__ __forceinline__ unsigned short f2bf(float f) {
    union { float f; unsigned u; } v; v.f = f;
    unsigned r = v.u + 0x7FFF + ((v.u >> 16) & 1);   // round-to-nearest-even
    return (unsigned short)(r >> 16);
}
__device__ __forceinline__ float bf2f(unsigned short h) {
    union { unsigned u; float f; } v; v.u = ((unsigned)h) << 16;
    return v.f;
}

typedef const __attribute__((address_space(1))) unsigned int* gas_ptr;
typedef __attribute__((address_space(3))) unsigned int* las_ptr;
__device__ __forceinline__ void lds_load16(const void* g, void* l) {
    __builtin_amdgcn_global_load_lds((gas_ptr)g, (las_ptr)l, 16, 0, 0);
}

__device__ __forceinline__ float4 f4add(float4 a, float4 b) {
    return make_float4(a.x + b.x, a.y + b.y, a.z + b.z, a.w + b.w);
}

// accumulate a bf16x4 fragment into a float4
__device__ __forceinline__ void accum_bf4(float4& a, ushort4 v) {
    a.x += bf2f(v.x); a.y += bf2f(v.y); a.z += bf2f(v.z); a.w += bf2f(v.w);
}

// ======================= TILED LAYOUT =======================
// All bf16 GEMM operands/activations use feature-tiled layout T[K/32][ROWS][32]:
//   element (row, k) at ((k>>5)*ROWS + row)*32 + (k&31).
// This is exactly the GEMM's 32-k staging granule (so staging = same 16B/lane
// loads, new base math), and it makes a 32-feature slice CONTIGUOUS (3.2 MB for
// g) so the edge-gather can run pass-per-slice with the slice L2-resident.

// ---------------- fused prep: zero counts/fillpos + split W1/W2 + x->bf16 (tiled) ----------------

__global__ __launch_bounds__(256) void prep_cvt_kernel(
        const float* __restrict__ x, const float* __restrict__ W1, const float* __restrict__ W2,
        int* __restrict__ counts, int* __restrict__ fillpos,
        unsigned short* __restrict__ w1hi, unsigned short* __restrict__ w1lo,
        unsigned short* __restrict__ w2hi, unsigned short* __restrict__ w2lo,
        unsigned short* __restrict__ xbf, int N) {
    int i = blockIdx.x * 256 + threadIdx.x;
    const int n0 = N;                 // zero range
    const int n1 = FEAT * HID;        // W1 split+transpose
    const int n2 = HID * HID;        // W2 split+transpose
    const int n3 = N * FEAT / 8;      // x -> bf16 (8 elems/item)
    if (i < n0) { counts[i] = 0; fillpos[i] = 0; return; }
    i -= n0;
    if (i < n1) {
        int k = i / HID, nn = i % HID;
        float f = W1[i];
        unsigned short h = f2bf(f);
        size_t t = ((size_t)(k >> 5) * HID + nn) * 32 + (k & 31);
        w1hi[t] = h;
        w1lo[t] = f2bf(f - bf2f(h));
        return;
    }
    i -= n1;
    if (i < n2) {
        int k = i / HID, nn = i % HID;
        float f = W2[i];
        unsigned short h = f2bf(f);
        size_t t = ((size_t)(k >> 5) * HID + nn) * 32 + (k & 31);
        w2hi[t] = h;
        w2lo[t] = f2bf(f - bf2f(h));
        return;
    }
    i -= n2;
    if (i < n3) {
        int r  = i >> 6;              // node (FEAT/8 = 64 chunks per row)
        int f0 = (i & 63) << 3;       // feature offset 0..504 step 8
        const float4* xp = (const float4*)x;
        float4 a = xp[2 * i], b = xp[2 * i + 1];
        float f[8] = {a.x, a.y, a.z, a.w, b.x, b.y, b.z, b.w};
        short8 h;
#pragma unroll
        for (int j = 0; j < 8; ++j) h[j] = (short)f2bf(f[j]);
        size_t t = ((size_t)(f0 >> 5) * N + r) * 32 + (f0 & 31);
        *(short8*)(xbf + t) = h;
    }
}

// ---------------- CSR build ----------------

__global__ void hist_kernel(const int* __restrict__ dst, int* __restrict__ counts, int E) {
    int e = blockIdx.x * 256 + threadIdx.x;
    if (e < E) atomicAdd(&counts[dst[e]], 1);
}

__global__ void scan_block_kernel(const int* __restrict__ counts, int* __restrict__ row_ptr,
                                  int* __restrict__ blocksums, int n) {
    __shared__ int s[256];
    int tid = threadIdx.x;
    int i = blockIdx.x * 256 + tid;
    int v = (i < n) ? counts[i] : 0;
    s[tid] = v; __syncthreads();
    for (int off = 1; off < 256; off <<= 1) {
        int t = (tid >= off) ? s[tid - off] : 0;
        __syncthreads();
        s[tid] += t;
        __syncthreads();
    }
    if (i < n) row_ptr[i] = s[tid] - v;
    if (tid == 255) blocksums[blockIdx.x] = s[255];
}

__global__ void finalize_rowptr_kernel(int* __restrict__ row_ptr, const int* __restrict__ blocksums,
                                       const int* __restrict__ counts, float* __restrict__ inv_sqrt,
                                       int n, int E, int nb) {
    __shared__ int s[256];
    __shared__ int excl[256];
    int tid = threadIdx.x;
    int v = (tid < nb) ? blocksums[tid] : 0;
    s[tid] = v; __syncthreads();
    for (int off = 1; off < 256; off <<= 1) {
        int t = (tid >= off) ? s[tid - off] : 0;
        __syncthreads();
        s[tid] += t;
        __syncthreads();
    }
    excl[tid] = s[tid] - v;
    __syncthreads();
    int i = blockIdx.x * 256 + tid;
    if (i < n) {
        row_ptr[i] += excl[i >> 8];
        inv_sqrt[i] = rsqrtf((float)(counts[i] + 1));
    }
    if (i == 0) row_ptr[n] = E;
}

__global__ void fill_kernel(const int* __restrict__ src, const int* __restrict__ dst,
                            const int* __restrict__ row_ptr, int* __restrict__ fillpos,
                            int* __restrict__ src_sorted, int E) {
    int e = blockIdx.x * 256 + threadIdx.x;
    if (e < E) {
        int d = dst[e];
        int pos = row_ptr[d] + atomicAdd(&fillpos[d], 1);
        src_sorted[pos] = src[e];
    }
}

// ---------------- split-bf16 MFMA GEMM: 256x256 tile, depth-3 counted-vmcnt pipeline ----------------
// Structure unchanged from R6 (proven); only operand ADDRESSES switch to tiled layout.
// A tiled [K/32][M][32]; B tiled [K/32][HID][32]; C written tiled [HID/32][M][32].

template<int K>
__global__ __launch_bounds__(512) void gemm_mfma_pipe_kernel(
        const unsigned short* __restrict__ gA,
        const unsigned short* __restrict__ Wthi, const unsigned short* __restrict__ Wtlo,
        const float* __restrict__ inv_sqrt, unsigned short* __restrict__ C,
        int M) {
    constexpr int NT = K / 32;                 // 32-k tiles (16 for K=512, 8 for K=256)
    __shared__ unsigned short Abuf [3][16 * 512];
    __shared__ unsigned short Bhbuf[3][16 * 512];
    __shared__ unsigned short Blbuf[3][16 * 512];
    const int tid  = threadIdx.x;
    const int lane = tid & 63;
    const int w    = tid >> 6;        // wave 0..7
    const int wr   = w >> 2, wc = w & 3;
    const int lm   = lane & 15;
    const int lk8  = (lane >> 4) * 8;
    const int bm   = blockIdx.x * 256;

    f32x4v acc[8][4] = {};

    // staging pointers (tiled): element (row, k=t*32+lk8) at base + t*ROWS*32
    int ar0 = bm + 16 * w + lm;       if (ar0 >= M) ar0 = M - 1;
    int ar1 = bm + 128 + 16 * w + lm; if (ar1 >= M) ar1 = M - 1;
    const size_t tsA = (size_t)M * 32;            // A tile stride (ushorts)
    const size_t tsB = (size_t)HID * 32;          // B tile stride
    const unsigned short* gA0  = gA   + (size_t)ar0 * 32 + lk8;
    const unsigned short* gA1  = gA   + (size_t)ar1 * 32 + lk8;
    const unsigned short* gBh0 = Wthi + (size_t)(16 * (2 * w)     + lm) * 32 + lk8;
    const unsigned short* gBh1 = Wthi + (size_t)(16 * (2 * w + 1) + lm) * 32 + lk8;
    const unsigned short* gBl0 = Wtlo + (size_t)(16 * (2 * w)     + lm) * 32 + lk8;
    const unsigned short* gBl1 = Wtlo + (size_t)(16 * (2 * w + 1) + lm) * 32 + lk8;

    auto stage = [&](int buf, int t) {
        const size_t oA = (size_t)t * tsA;
        const size_t oB = (size_t)t * tsB;
        lds_load16(gA0  + oA, &Abuf [buf][w * 512]);
        lds_load16(gA1  + oA, &Abuf [buf][(8 + w) * 512]);
        lds_load16(gBh0 + oB, &Bhbuf[buf][(2 * w) * 512]);
        lds_load16(gBh1 + oB, &Bhbuf[buf][(2 * w + 1) * 512]);
        lds_load16(gBl0 + oB, &Blbuf[buf][(2 * w) * 512]);
        lds_load16(gBl1 + oB, &Blbuf[buf][(2 * w + 1) * 512]);
    };

    auto compute = [&](int buf) {
        short8 ah[8], bh[4], bv[4];
#pragma unroll
        for (int j = 0; j < 4; ++j) {
            bh[j] = *(const short8*)&Bhbuf[buf][(wc * 4 + j) * 512 + lane * 8];
            bv[j] = *(const short8*)&Blbuf[buf][(wc * 4 + j) * 512 + lane * 8];
        }
#pragma unroll
        for (int i = 0; i < 8; ++i)
            ah[i] = *(const short8*)&Abuf[buf][(wr * 8 + i) * 512 + lane * 8];
#pragma unroll
        for (int i = 0; i < 8; ++i)
#pragma unroll
            for (int j = 0; j < 4; ++j) {
                acc[i][j] = __builtin_amdgcn_mfma_f32_16x16x32_bf16(ah[i], bh[j], acc[i][j], 0, 0, 0);
                acc[i][j] = __builtin_amdgcn_mfma_f32_16x16x32_bf16(ah[i], bv[j], acc[i][j], 0, 0, 0);
            }
    };

    // prologue: fill the 3-deep pipe (18 loads/wave), wait tile 0 only (vmcnt(12)), publish
    stage(0, 0); stage(1, 1); stage(2, 2);
    asm volatile("s_waitcnt vmcnt(12)" ::: "memory");
    __builtin_amdgcn_s_barrier();
    __builtin_amdgcn_sched_barrier(0);

#pragma unroll
    for (int t = 0; t < NT; ++t) {
        const int buf = t % 3;
        compute(buf);                          // read tile t
        __builtin_amdgcn_s_barrier();          // all waves done reading buf
        __builtin_amdgcn_sched_barrier(0);
        if (t + 3 < NT) {
            stage(buf, t + 3);                 // refill freed buffer; in-flight: t+1,t+2,t+3
            asm volatile("s_waitcnt vmcnt(12)" ::: "memory");   // wait tile t+1 landed
        } else if (t + 2 < NT) {
            asm volatile("s_waitcnt vmcnt(6)" ::: "memory");    // in-flight: t+1,t+2
        } else if (t + 1 < NT) {
            asm volatile("s_waitcnt vmcnt(0)" ::: "memory");    // in-flight: t+1 only
        }
        __builtin_amdgcn_s_barrier();          // publish tile t+1
        __builtin_amdgcn_sched_barrier(0);
    }

    // ---- epilogue: C/D layout col=lane&15, row=(lane>>4)*4+r ; store bf16 TILED ----
    const int orow_base = bm + wr * 128;
    const int rq = (lane >> 4) * 4;
#pragma unroll
    for (int i = 0; i < 8; ++i) {
#pragma unroll
        for (int r = 0; r < 4; ++r) {
            int row = orow_base + i * 16 + rq + r;
            if (row >= M) continue;
            float s = inv_sqrt[row];
#pragma unroll
            for (int j = 0; j < 4; ++j) {
                // col = wc*64 + j*16 + lm  ->  tile wc*2+(j>>1), within lm+(j&1)*16
                size_t off = ((size_t)(wc * 2 + (j >> 1)) * M + row) * 32 + lm + (j & 1) * 16;
                C[off] = f2bf(acc[i][j][r] * s);
            }
        }
    }
}

// ---------------- fp32 vector GEMM for layer 3 (A given as hi/lo bf16, TILED) ----------------

__global__ __launch_bounds__(256) void gemm_scaled_hl_kernel(
        const unsigned short* __restrict__ Ahi, const unsigned short* __restrict__ Alo,
        const float* __restrict__ W,
        const float* __restrict__ inv_sqrt, float* __restrict__ C,
        int M, int K, int Ncol) {
    __shared__ float As[16][64];
    __shared__ float Ws[16][64];
    int tid = threadIdx.x;
    int tm = tid >> 4;
    int tn = tid & 15;
    int bm = blockIdx.x * 64;
    int bn = blockIdx.y * 64;

    float acc[4][4] = {};

    int lr = tid >> 2;
    int lc = (tid & 3) << 2;
    int wr = tid >> 4;
    int wc = (tid & 15) << 2;
    int arow = bm + lr;
    bool aok = arow < M;
    bool wok = (bn + wc) < Ncol;

    for (int k0 = 0; k0 < K; k0 += 16) {
        float4 av = make_float4(0.f, 0.f, 0.f, 0.f);
        if (aok) {
            size_t ta = ((size_t)(k0 >> 5) * M + arow) * 32 + (k0 & 16) + lc;
            ushort4 hv = *(const ushort4*)(Ahi + ta);
            ushort4 lv = *(const ushort4*)(Alo + ta);
            av.x = bf2f(hv.x) + bf2f(lv.x);
            av.y = bf2f(hv.y) + bf2f(lv.y);
            av.z = bf2f(hv.z) + bf2f(lv.z);
            av.w = bf2f(hv.w) + bf2f(lv.w);
        }
        As[lc + 0][lr] = av.x; As[lc + 1][lr] = av.y;
        As[lc + 2][lr] = av.z; As[lc + 3][lr] = av.w;

        float4 wv = make_float4(0.f, 0.f, 0.f, 0.f);
        if (wok) wv = *(const float4*)(W + (size_t)(k0 + wr) * Ncol + bn + wc);
        *(float4*)&Ws[wr][wc] = wv;
        __syncthreads();

#pragma unroll
        for (int k = 0; k < 16; ++k) {
            const float4 a4 = *(const float4*)&As[k][tm << 2];
            const float4 b4 = *(const float4*)&Ws[k][tn << 2];
            float a[4] = {a4.x, a4.y, a4.z, a4.w};
            float b[4] = {b4.x, b4.y, b4.z, b4.w};
#pragma unroll
            for (int i = 0; i < 4; ++i)
#pragma unroll
                for (int j = 0; j < 4; ++j)
                    acc[i][j] = fmaf(a[i], b[j], acc[i][j]);
        }
        __syncthreads();
    }

#pragma unroll
    for (int i = 0; i < 4; ++i) {
        int row = bm + (tm << 2) + i;
        if (row >= M) continue;
        float s = inv_sqrt[row];
        int col = bn + (tn << 2);
        if (col < Ncol) {
            float4 o = make_float4(acc[i][0] * s, acc[i][1] * s, acc[i][2] * s, acc[i][3] * s);
            *(float4*)&C[(size_t)row * Ncol + col] = o;
        }
    }
}

// ---------------- aggregation: PASS-PER-32-FEATURE-SLICE over tiled g ----------------
// grid = ((N+3)/4, 8). Pass p gathers only slice g_t[p] (N x 32 bf16 = 3.2 MB -> fits
// every XCD's 4 MB L2; dispatch is pass-major so the slice stays hot). One wave per node.
// Lane -> edge-group gi=lane>>3 (8 edges in flight per load), 8 B chunk ci=lane&7.
// Indices staged via LDS (uniform ds_read, NOT varying-selector shfl - R8 lesson).
// Cross-group combine: 3-step shfl_xor(8/16/32). Output written tiled [8][N][32].

template<bool WRITE_LO>
__global__ __launch_bounds__(256) void agg_bn_tiled_kernel(
        const unsigned short* __restrict__ g, const int* __restrict__ row_ptr,
        const int* __restrict__ srcs, const float* __restrict__ inv_sqrt,
        const float* __restrict__ bias, const float* __restrict__ gamma,
        const float* __restrict__ beta, const float* __restrict__ mean,
        const float* __restrict__ var,
        unsigned short* __restrict__ out_hi, unsigned short* __restrict__ out_lo, int n) {
    __shared__ int sidx[4][64];
    const int wv   = threadIdx.x >> 6;
    const int lane = threadIdx.x & 63;
    const int node = (blockIdx.x << 2) + wv;
    const int p    = blockIdx.y;              // feature-slice pass 0..7
    if (node >= n) return;
    const int gi = lane >> 3;                 // edge group 0..7
    const int ci = lane & 7;                  // ushort4 chunk within 64 B slice row
    const ushort4* gp = (const ushort4*)(g + (size_t)p * n * 32);   // slice: n rows x 8 chunks

    float4 a0 = {0.f,0.f,0.f,0.f}, a1 = {0.f,0.f,0.f,0.f};

    if (gi == 0) {                            // self-loop, counted once
        ushort4 v = gp[(size_t)node * 8 + ci];
        accum_bf4(a0, v);
    }
    int beg = row_ptr[node];
    int cnt = row_ptr[node + 1] - beg;

    for (int base = 0; base < cnt; base += 64) {
        int m = cnt - base; if (m > 64) m = 64;
        sidx[wv][lane] = (lane < m) ? srcs[beg + base + lane] : 0;
        int j = 0;
        for (; j + 16 <= m; j += 16) {        // 16 edges = 2 wave-loads in flight
            int s0 = sidx[wv][j + gi];
            int s1 = sidx[wv][j + 8 + gi];
            ushort4 v0 = gp[(size_t)s0 * 8 + ci];
            ushort4 v1 = gp[(size_t)s1 * 8 + ci];
            accum_bf4(a0, v0);
            accum_bf4(a1, v1);
        }
        for (; j < m; j += 8) {               // tail (groups >= m-j masked)
            int jj = j + gi;
            int s = sidx[wv][jj < m ? jj : j];
            ushort4 v = gp[(size_t)s * 8 + ci];
            if (jj < m) accum_bf4(a0, v);
        }
    }
    float4 acc = f4add(a0, a1);
#pragma unroll
    for (int off = 8; off < 64; off <<= 1) {  // combine the 8 edge-groups
        acc.x += __shfl_xor(acc.x, off);
        acc.y += __shfl_xor(acc.y, off);
        acc.z += __shfl_xor(acc.z, off);
        acc.w += __shfl_xor(acc.w, off);
    }

    float inv = inv_sqrt[node];
    int fb = p * 8 + ci;                      // float4 index into per-feature params
    float4 b4 = ((const float4*)bias)[fb];
    float4 ga = ((const float4*)gamma)[fb];
    float4 be = ((const float4*)beta)[fb];
    float4 mu = ((const float4*)mean)[fb];
    float4 vr = ((const float4*)var)[fb];
    float4 o;
    o.x = fmaxf((acc.x * inv + b4.x - mu.x) * (ga.x * rsqrtf(vr.x + EPS)) + be.x, 0.f);
    o.y = fmaxf((acc.y * inv + b4.y - mu.y) * (ga.y * rsqrtf(vr.y + EPS)) + be.y, 0.f);
    o.z = fmaxf((acc.z * inv + b4.z - mu.z) * (ga.z * rsqrtf(vr.z + EPS)) + be.z, 0.f);
    o.w = fmaxf((acc.w * inv + b4.w - mu.w) * (ga.w * rsqrtf(vr.w + EPS)) + be.w, 0.f);
    ushort4 oh;
    oh.x = f2bf(o.x); oh.y = f2bf(o.y); oh.z = f2bf(o.z); oh.w = f2bf(o.w);
    size_t widx = (size_t)p * n * 8 + (size_t)node * 8 + ci;
    if (gi == 0) ((ushort4*)out_hi)[widx] = oh;
    if (WRITE_LO && gi == 1) {
        ushort4 ol;
        ol.x = f2bf(o.x - bf2f(oh.x));
        ol.y = f2bf(o.y - bf2f(oh.y));
        ol.z = f2bf(o.z - bf2f(oh.z));
        ol.w = f2bf(o.w - bf2f(oh.w));
        ((ushort4*)out_lo)[widx] = ol;
    }
}

// ---------------- final aggregation (C=40): fp32 row-major (unchanged) ----------------

__global__ __launch_bounds__(256) void agg_final_kernel(
        const float* __restrict__ g, const int* __restrict__ row_ptr,
        const int* __restrict__ srcs, const float* __restrict__ inv_sqrt,
        const float* __restrict__ bias, float* __restrict__ out, int n) {
    int node = (blockIdx.x << 2) + (threadIdx.x >> 6);
    int lane = threadIdx.x & 63;
    if (node >= n) return;
    int flane = (lane < CLS) ? lane : 0;       // clamped gather lane; store masked below
    float acc0 = g[(size_t)node * CLS + flane];
    float acc1 = 0.f;
    int beg = row_ptr[node];
    int cnt = row_ptr[node + 1] - beg;

    for (int base = 0; base < cnt; base += 64) {
        int m = cnt - base; if (m > 64) m = 64;
        int idx = (lane < m) ? srcs[beg + base + lane] : 0;
        int j = 0;
        for (; j + 8 <= m; j += 8) {
            int s0 = __shfl(idx, j + 0), s1 = __shfl(idx, j + 1);
            int s2 = __shfl(idx, j + 2), s3 = __shfl(idx, j + 3);
            int s4 = __shfl(idx, j + 4), s5 = __shfl(idx, j + 5);
            int s6 = __shfl(idx, j + 6), s7 = __shfl(idx, j + 7);
            float v0 = g[(size_t)s0 * CLS + flane];
            float v1 = g[(size_t)s1 * CLS + flane];
            float v2 = g[(size_t)s2 * CLS + flane];
            float v3 = g[(size_t)s3 * CLS + flane];
            float v4 = g[(size_t)s4 * CLS + flane];
            float v5 = g[(size_t)s5 * CLS + flane];
            float v6 = g[(size_t)s6 * CLS + flane];
            float v7 = g[(size_t)s7 * CLS + flane];
            acc0 += (v0 + v1) + (v2 + v3);
            acc1 += (v4 + v5) + (v6 + v7);
        }
        for (; j < m; ++j) {
            int s = __shfl(idx, j);
            acc0 += g[(size_t)s * CLS + flane];
        }
    }
    if (lane < CLS)
        out[(size_t)node * CLS + lane] = (acc0 + acc1) * inv_sqrt[node] + bias[lane];
}

// ---------------- launch ----------------

extern "C" void kernel_launch(void* const* d_in, const int* in_sizes, int n_in,
                              void* d_out, int out_size, void* d_ws, size_t ws_size,
                              hipStream_t stream) {
    const float* x     = (const float*)d_in[0];
    const int*   edges = (const int*)d_in[1];
    const float* W1    = (const float*)d_in[2];
    const float* b1    = (const float*)d_in[3];
    const float* W2    = (const float*)d_in[4];
    const float* b2    = (const float*)d_in[5];
    const float* W3    = (const float*)d_in[6];
    const float* b3    = (const float*)d_in[7];
    const float* gamma = (const float*)d_in[8];
    const float* beta  = (const float*)d_in[9];
    const float* mean  = (const float*)d_in[10];
    const float* var   = (const float*)d_in[11];

    const int N = in_sizes[0] / FEAT;   // 50000
    const int E = in_sizes[1] / 2;      // 800000
    const int* src = edges;
    const int* dst = edges + E;

    char* ws = (char*)d_ws;
    auto alloc = [&](size_t bytes) -> char* {
        char* p = ws;
        ws += (bytes + 255) & ~(size_t)255;
        return p;
    };
    int*   counts     = (int*)  alloc((size_t)N * 4);
    int*   fillpos    = (int*)  alloc((size_t)N * 4);
    int*   row_ptr    = (int*)  alloc((size_t)(N + 1) * 4);
    int*   blocksums  = (int*)  alloc(256 * 4);
    float* inv_sqrt   = (float*)alloc((size_t)N * 4);
    int*   src_sorted = (int*)  alloc((size_t)E * 4);
    unsigned short* w1hi = (unsigned short*)alloc((size_t)FEAT * HID * 2);
    unsigned short* w1lo = (unsigned short*)alloc((size_t)FEAT * HID * 2);
    unsigned short* w2hi = (unsigned short*)alloc((size_t)HID * HID * 2);
    unsigned short* w2lo = (unsigned short*)alloc((size_t)HID * HID * 2);
    // g: tiled bf16 [8][N][32] for layers 1-2 (25.6 MB); reused as fp32 N*CLS for layer 3
    unsigned short* g    = (unsigned short*)alloc((size_t)N * HID * 2);
    unsigned short* h_hi = (unsigned short*)alloc((size_t)N * HID * 2); // 25.6 MB (tiled)
    unsigned short* h_lo = (unsigned short*)alloc((size_t)N * HID * 2); // 25.6 MB (tiled)
    // xbf (tiled [16][N][32] bf16 = 51.2 MB) aliases h_hi+h_lo: dead once GEMM1 completes.
    unsigned short* xbf  = h_hi;

    int nb = (N + 255) / 256;           // 196
    int eb = (E + 255) / 256;

    // 1) fused prep: zero + W1/W2 split + x->bf16 (all tiled)
    int prep_items = N + FEAT * HID + HID * HID + N * FEAT / 8;
    prep_cvt_kernel<<<(prep_items + 255) / 256, 256, 0, stream>>>(
        x, W1, W2, counts, fillpos, w1hi, w1lo, w2hi, w2lo, xbf, N);
    // 2-5) CSR build
    hist_kernel<<<eb, 256, 0, stream>>>(dst, counts, E);
    scan_block_kernel<<<nb, 256, 0, stream>>>(counts, row_ptr, blocksums, N);
    finalize_rowptr_kernel<<<nb, 256, 0, stream>>>(row_ptr, blocksums, counts, inv_sqrt, N, E, nb);
    fill_kernel<<<eb, 256, 0, stream>>>(src, dst, row_ptr, fillpos, src_sorted, E);

    dim3 pipe_grid((N + 255) / 256);    // 196 blocks, 256 rows x full 256 cols per block
    dim3 gemm3_grid((N + 63) / 64, 1);
    dim3 aggt_grid((N + 3) / 4, 8);     // pass-major feature slices
    dim3 agg_grid((N + 3) / 4);

    // 6-7) layer 1: tiled GEMM; agg1 -> h_hi tiled bf16
    gemm_mfma_pipe_kernel<FEAT><<<pipe_grid, 512, 0, stream>>>(
        xbf, w1hi, w1lo, inv_sqrt, g, N);
    agg_bn_tiled_kernel<false><<<aggt_grid, 256, 0, stream>>>(g, row_ptr, src_sorted, inv_sqrt,
                                                              b1, gamma, beta, mean, var, h_hi, nullptr, N);
    // 8-9) layer 2: tiled GEMM; agg2 -> h_hi/h_lo tiled for fp32 GEMM3
    gemm_mfma_pipe_kernel<HID><<<pipe_grid, 512, 0, stream>>>(
        h_hi, w2hi, w2lo, inv_sqrt, g, N);
    agg_bn_tiled_kernel<true><<<aggt_grid, 256, 0, stream>>>(g, row_ptr, src_sorted, inv_sqrt,
                                                             b2, gamma, beta, mean, var, h_hi, h_lo, N);
    // 10-11) layer 3: fp32 vector GEMM reading tiled hi/lo; fp32 g3 (reuses g); final agg
    float* g3 = (float*)g;
    gemm_scaled_hl_kernel<<<gemm3_grid, 256, 0, stream>>>(h_hi, h_lo, W3, inv_sqrt, g3, N, HID, CLS);
    agg_final_kernel<<<agg_grid, 256, 0, stream>>>(g3, row_ptr, src_sorted, inv_sqrt,
                                                   b3, (float*)d_out, N);
}

// Round 12
// 517.711 us; speedup vs baseline: 1.3692x; 1.3692x over previous
//
#include <hip/hip_runtime.h>
#include <cstdint>
#include <cstddef>

#define FEAT 512
#define HID 256
#define CLS 40
#define EPS 1e-5f

typedef __attribute__((ext_vector_type(8))) short short8;
typedef __attribute__((ext_vector_type(4))) float f32x4v;
typedef __attribute__((ext_vector_type(4))) unsigned short u16x4;   // clang vector: legal for nontemporal builtins

// ---------------- helpers ----------------

__device__ __forceinline__ unsigned short f2bf(float f) {
    union { float f; unsigned u; } v; v.f = f;
    unsigned r = v.u + 0x7FFF + ((v.u >> 16) & 1);   // round-to-nearest-even
    return (unsigned short)(r >> 16);
}
__device__ __forceinline__ float bf2f(unsigned short h) {
    union { unsigned u; float f; } v; v.u = ((unsigned)h) << 16;
    return v.f;
}

typedef const __attribute__((address_space(1))) unsigned int* gas_ptr;
typedef __attribute__((address_space(3))) unsigned int* las_ptr;
__device__ __forceinline__ void lds_load16(const void* g, void* l) {
    __builtin_amdgcn_global_load_lds((gas_ptr)g, (las_ptr)l, 16, 0, 0);
}

__device__ __forceinline__ float4 f4add(float4 a, float4 b) {
    return make_float4(a.x + b.x, a.y + b.y, a.z + b.z, a.w + b.w);
}

// accumulate a bf16x4 row fragment into a float4
__device__ __forceinline__ void accum_bf4(float4& a, ushort4 v) {
    a.x += bf2f(v.x); a.y += bf2f(v.y); a.z += bf2f(v.z); a.w += bf2f(v.w);
}

// ---------------- fused prep: zero counts/fillpos + split W1/W2 + x->bf16 ----------------

__global__ __launch_bounds__(256) void prep_cvt_kernel(
        const float* __restrict__ x, const float* __restrict__ W1, const float* __restrict__ W2,
        int* __restrict__ counts, int* __restrict__ fillpos,
        unsigned short* __restrict__ w1hi, unsigned short* __restrict__ w1lo,
        unsigned short* __restrict__ w2hi, unsigned short* __restrict__ w2lo,
        unsigned short* __restrict__ xbf, int N) {
    int i = blockIdx.x * 256 + threadIdx.x;
    const int n0 = N;                 // zero range
    const int n1 = FEAT * HID;        // W1 split+transpose
    const int n2 = HID * HID;         // W2 split+transpose
    const int n3 = N * FEAT / 8;      // x -> bf16 (8 elems/item)
    if (i < n0) { counts[i] = 0; fillpos[i] = 0; return; }
    i -= n0;
    if (i < n1) {
        int k = i / HID, n = i % HID;
        float f = W1[i];
        unsigned short h = f2bf(f);
        w1hi[(size_t)n * FEAT + k] = h;
        w1lo[(size_t)n * FEAT + k] = f2bf(f - bf2f(h));
        return;
    }
    i -= n1;
    if (i < n2) {
        int k = i / HID, n = i % HID;
        float f = W2[i];
        unsigned short h = f2bf(f);
        w2hi[(size_t)n * HID + k] = h;
        w2lo[(size_t)n * HID + k] = f2bf(f - bf2f(h));
        return;
    }
    i -= n2;
    if (i < n3) {
        const float4* xp = (const float4*)x;
        float4 a = xp[2 * i], b = xp[2 * i + 1];
        float f[8] = {a.x, a.y, a.z, a.w, b.x, b.y, b.z, b.w};
        short8 h;
#pragma unroll
        for (int j = 0; j < 8; ++j) h[j] = (short)f2bf(f[j]);
        ((short8*)xbf)[i] = h;
    }
}

// ---------------- CSR build ----------------

__global__ void hist_kernel(const int* __restrict__ dst, int* __restrict__ counts, int E) {
    int e = blockIdx.x * 256 + threadIdx.x;
    if (e < E) atomicAdd(&counts[dst[e]], 1);
}

__global__ void scan_block_kernel(const int* __restrict__ counts, int* __restrict__ row_ptr,
                                  int* __restrict__ blocksums, int n) {
    __shared__ int s[256];
    int tid = threadIdx.x;
    int i = blockIdx.x * 256 + tid;
    int v = (i < n) ? counts[i] : 0;
    s[tid] = v; __syncthreads();
    for (int off = 1; off < 256; off <<= 1) {
        int t = (tid >= off) ? s[tid - off] : 0;
        __syncthreads();
        s[tid] += t;
        __syncthreads();
    }
    if (i < n) row_ptr[i] = s[tid] - v;
    if (tid == 255) blocksums[blockIdx.x] = s[255];
}

// scan_sums folded in: every block redundantly scans blocksums (nb<=256) in LDS.
__global__ void finalize_rowptr_kernel(int* __restrict__ row_ptr, const int* __restrict__ blocksums,
                                       const int* __restrict__ counts, float* __restrict__ inv_sqrt,
                                       int n, int E, int nb) {
    __shared__ int s[256];
    __shared__ int excl[256];
    int tid = threadIdx.x;
    int v = (tid < nb) ? blocksums[tid] : 0;
    s[tid] = v; __syncthreads();
    for (int off = 1; off < 256; off <<= 1) {
        int t = (tid >= off) ? s[tid - off] : 0;
        __syncthreads();
        s[tid] += t;
        __syncthreads();
    }
    excl[tid] = s[tid] - v;
    __syncthreads();
    int i = blockIdx.x * 256 + tid;
    if (i < n) {
        row_ptr[i] += excl[i >> 8];
        inv_sqrt[i] = rsqrtf((float)(counts[i] + 1));
    }
    if (i == 0) row_ptr[n] = E;
}

__global__ void fill_kernel(const int* __restrict__ src, const int* __restrict__ dst,
                            const int* __restrict__ row_ptr, int* __restrict__ fillpos,
                            int* __restrict__ src_sorted, int E) {
    int e = blockIdx.x * 256 + threadIdx.x;
    if (e < E) {
        int d = dst[e];
        int pos = row_ptr[d] + atomicAdd(&fillpos[d], 1);
        src_sorted[pos] = src[e];
    }
}

// ---------------- split-bf16 MFMA GEMM: 256x256 tile, depth-3 counted-vmcnt pipeline ----------------
// (unchanged from R6/R7 - delivery-model-confirmed)

template<int K>
__global__ __launch_bounds__(512) void gemm_mfma_pipe_kernel(
        const unsigned short* __restrict__ gA,
        const unsigned short* __restrict__ Wthi, const unsigned short* __restrict__ Wtlo,
        const float* __restrict__ inv_sqrt, unsigned short* __restrict__ C,
        int M) {
    constexpr int NT = K / 32;                 // 32-k tiles (16 for K=512, 8 for K=256)
    __shared__ unsigned short Abuf [3][16 * 512];   // [buf][mblk][16r x 32k frag-linear]
    __shared__ unsigned short Bhbuf[3][16 * 512];   // [buf][nblk][...]
    __shared__ unsigned short Blbuf[3][16 * 512];
    const int tid  = threadIdx.x;
    const int lane = tid & 63;
    const int w    = tid >> 6;        // wave 0..7
    const int wr   = w >> 2, wc = w & 3;
    const int lm   = lane & 15;
    const int lk8  = (lane >> 4) * 8;
    const int bm   = blockIdx.x * 256;

    f32x4v acc[8][4] = {};

    // --- staging pointers: wave w stages A m-blocks w, w+8; Bhi/Blo n-blocks 2w, 2w+1 ---
    int ar0 = bm + 16 * w + lm;       if (ar0 >= M) ar0 = M - 1;
    int ar1 = bm + 128 + 16 * w + lm; if (ar1 >= M) ar1 = M - 1;
    const unsigned short* gA0  = gA   + (size_t)ar0 * K + lk8;
    const unsigned short* gA1  = gA   + (size_t)ar1 * K + lk8;
    const unsigned short* gBh0 = Wthi + (size_t)(16 * (2 * w)     + lm) * K + lk8;
    const unsigned short* gBh1 = Wthi + (size_t)(16 * (2 * w + 1) + lm) * K + lk8;
    const unsigned short* gBl0 = Wtlo + (size_t)(16 * (2 * w)     + lm) * K + lk8;
    const unsigned short* gBl1 = Wtlo + (size_t)(16 * (2 * w + 1) + lm) * K + lk8;

    auto stage = [&](int buf, int t) {
        const int kg = t * 32;
        lds_load16(gA0  + kg, &Abuf [buf][w * 512]);
        lds_load16(gA1  + kg, &Abuf [buf][(8 + w) * 512]);
        lds_load16(gBh0 + kg, &Bhbuf[buf][(2 * w) * 512]);
        lds_load16(gBh1 + kg, &Bhbuf[buf][(2 * w + 1) * 512]);
        lds_load16(gBl0 + kg, &Blbuf[buf][(2 * w) * 512]);
        lds_load16(gBl1 + kg, &Blbuf[buf][(2 * w + 1) * 512]);
    };

    auto compute = [&](int buf) {
        short8 ah[8], bh[4], bv[4];
#pragma unroll
        for (int j = 0; j < 4; ++j) {
            bh[j] = *(const short8*)&Bhbuf[buf][(wc * 4 + j) * 512 + lane * 8];
            bv[j] = *(const short8*)&Blbuf[buf][(wc * 4 + j) * 512 + lane * 8];
        }
#pragma unroll
        for (int i = 0; i < 8; ++i)
            ah[i] = *(const short8*)&Abuf[buf][(wr * 8 + i) * 512 + lane * 8];
#pragma unroll
        for (int i = 0; i < 8; ++i)
#pragma unroll
            for (int j = 0; j < 4; ++j) {
                acc[i][j] = __builtin_amdgcn_mfma_f32_16x16x32_bf16(ah[i], bh[j], acc[i][j], 0, 0, 0);
                acc[i][j] = __builtin_amdgcn_mfma_f32_16x16x32_bf16(ah[i], bv[j], acc[i][j], 0, 0, 0);
            }
    };

    // prologue: fill the 3-deep pipe (18 loads/wave), wait tile 0 only (vmcnt(12)), publish
    stage(0, 0); stage(1, 1); stage(2, 2);
    asm volatile("s_waitcnt vmcnt(12)" ::: "memory");
    __builtin_amdgcn_s_barrier();
    __builtin_amdgcn_sched_barrier(0);

#pragma unroll
    for (int t = 0; t < NT; ++t) {
        const int buf = t % 3;
        compute(buf);                          // read tile t
        __builtin_amdgcn_s_barrier();          // all waves done reading buf
        __builtin_amdgcn_sched_barrier(0);
        if (t + 3 < NT) {
            stage(buf, t + 3);                 // refill freed buffer; in-flight: t+1,t+2,t+3
            asm volatile("s_waitcnt vmcnt(12)" ::: "memory");   // wait tile t+1 landed
        } else if (t + 2 < NT) {
            asm volatile("s_waitcnt vmcnt(6)" ::: "memory");    // in-flight: t+1,t+2
        } else if (t + 1 < NT) {
            asm volatile("s_waitcnt vmcnt(0)" ::: "memory");    // in-flight: t+1 only
        }
        __builtin_amdgcn_s_barrier();          // publish tile t+1
        __builtin_amdgcn_sched_barrier(0);
    }

    // ---- epilogue: C/D layout col=lane&15, row=(lane>>4)*4+r ; store bf16, Ncol=HID ----
    const int orow_base = bm + wr * 128;
    const int ocol_base = wc * 64 + lm;
    const int rq = (lane >> 4) * 4;
#pragma unroll
    for (int i = 0; i < 8; ++i) {
#pragma unroll
        for (int r = 0; r < 4; ++r) {
            int row = orow_base + i * 16 + rq + r;
            if (row >= M) continue;
            float s = inv_sqrt[row];
            size_t rb = (size_t)row * HID;
#pragma unroll
            for (int j = 0; j < 4; ++j)
                C[rb + ocol_base + j * 16] = f2bf(acc[i][j][r] * s);
        }
    }
}

// ---------------- fp32 vector GEMM for layer 3 (A given as hi/lo bf16) ----------------

__global__ __launch_bounds__(256) void gemm_scaled_hl_kernel(
        const unsigned short* __restrict__ Ahi, const unsigned short* __restrict__ Alo,
        const float* __restrict__ W,
        const float* __restrict__ inv_sqrt, float* __restrict__ C,
        int M, int K, int Ncol) {
    __shared__ float As[16][64];
    __shared__ float Ws[16][64];
    int tid = threadIdx.x;
    int tm = tid >> 4;
    int tn = tid & 15;
    int bm = blockIdx.x * 64;
    int bn = blockIdx.y * 64;

    float acc[4][4] = {};

    int lr = tid >> 2;
    int lc = (tid & 3) << 2;
    int wr = tid >> 4;
    int wc = (tid & 15) << 2;
    int arow = bm + lr;
    bool aok = arow < M;
    bool wok = (bn + wc) < Ncol;
    const unsigned short* AhiRow = Ahi + (size_t)arow * K + lc;
    const unsigned short* AloRow = Alo + (size_t)arow * K + lc;

    for (int k0 = 0; k0 < K; k0 += 16) {
        float4 av = make_float4(0.f, 0.f, 0.f, 0.f);
        if (aok) {
            ushort4 hv = *(const ushort4*)(AhiRow + k0);
            ushort4 lv = *(const ushort4*)(AloRow + k0);
            av.x = bf2f(hv.x) + bf2f(lv.x);
            av.y = bf2f(hv.y) + bf2f(lv.y);
            av.z = bf2f(hv.z) + bf2f(lv.z);
            av.w = bf2f(hv.w) + bf2f(lv.w);
        }
        As[lc + 0][lr] = av.x; As[lc + 1][lr] = av.y;
        As[lc + 2][lr] = av.z; As[lc + 3][lr] = av.w;

        float4 wv = make_float4(0.f, 0.f, 0.f, 0.f);
        if (wok) wv = *(const float4*)(W + (size_t)(k0 + wr) * Ncol + bn + wc);
        *(float4*)&Ws[wr][wc] = wv;
        __syncthreads();

#pragma unroll
        for (int k = 0; k < 16; ++k) {
            const float4 a4 = *(const float4*)&As[k][tm << 2];
            const float4 b4 = *(const float4*)&Ws[k][tn << 2];
            float a[4] = {a4.x, a4.y, a4.z, a4.w};
            float b[4] = {b4.x, b4.y, b4.z, b4.w};
#pragma unroll
            for (int i = 0; i < 4; ++i)
#pragma unroll
                for (int j = 0; j < 4; ++j)
                    acc[i][j] = fmaf(a[i], b[j], acc[i][j]);
        }
        __syncthreads();
    }

#pragma unroll
    for (int i = 0; i < 4; ++i) {
        int row = bm + (tm << 2) + i;
        if (row >= M) continue;
        float s = inv_sqrt[row];
        int col = bn + (tn << 2);
        if (col < Ncol) {
            float4 o = make_float4(acc[i][0] * s, acc[i][1] * s, acc[i][2] * s, acc[i][3] * s);
            *(float4*)&C[(size_t)row * Ncol + col] = o;
        }
    }
}

// ---------------- aggregation (H=256): one wave per node; g is bf16, acc fp32 ----------------
// R7 structure (best measured: 62.4 us). Only change: NONTEMPORAL output stores
// (via clang ext-vector u16x4 - HIP ushort4 struct is rejected by the builtin) -
// outputs are never re-read inside this kernel, and normal stores evict the g rows
// the gather re-reads ~16x/node from L2.

template<bool WRITE_LO>
__global__ __launch_bounds__(256) void agg_bn_hl_kernel(
        const unsigned short* __restrict__ g, const int* __restrict__ row_ptr,
        const int* __restrict__ srcs, const float* __restrict__ inv_sqrt,
        const float* __restrict__ bias, const float* __restrict__ gamma,
        const float* __restrict__ beta, const float* __restrict__ mean,
        const float* __restrict__ var,
        unsigned short* __restrict__ out_hi, unsigned short* __restrict__ out_lo, int n) {
    int node = (blockIdx.x << 2) + (threadIdx.x >> 6);
    int lane = threadIdx.x & 63;
    if (node >= n) return;
    const ushort4* gp = (const ushort4*)g;   // 64 ushort4 per 256-elem row
    float4 acc0 = make_float4(0.f, 0.f, 0.f, 0.f);
    float4 acc1 = make_float4(0.f, 0.f, 0.f, 0.f);
    accum_bf4(acc0, gp[(size_t)node * 64 + lane]);   // self-loop
    int beg = row_ptr[node];
    int cnt = row_ptr[node + 1] - beg;

    for (int base = 0; base < cnt; base += 64) {
        int m = cnt - base; if (m > 64) m = 64;
        int idx = (lane < m) ? srcs[beg + base + lane] : 0;
        int j = 0;
        for (; j + 8 <= m; j += 8) {
            int s0 = __shfl(idx, j + 0), s1 = __shfl(idx, j + 1);
            int s2 = __shfl(idx, j + 2), s3 = __shfl(idx, j + 3);
            int s4 = __shfl(idx, j + 4), s5 = __shfl(idx, j + 5);
            int s6 = __shfl(idx, j + 6), s7 = __shfl(idx, j + 7);
            ushort4 v0 = gp[(size_t)s0 * 64 + lane];
            ushort4 v1 = gp[(size_t)s1 * 64 + lane];
            ushort4 v2 = gp[(size_t)s2 * 64 + lane];
            ushort4 v3 = gp[(size_t)s3 * 64 + lane];
            ushort4 v4 = gp[(size_t)s4 * 64 + lane];
            ushort4 v5 = gp[(size_t)s5 * 64 + lane];
            ushort4 v6 = gp[(size_t)s6 * 64 + lane];
            ushort4 v7 = gp[(size_t)s7 * 64 + lane];
            accum_bf4(acc0, v0); accum_bf4(acc0, v1);
            accum_bf4(acc0, v2); accum_bf4(acc0, v3);
            accum_bf4(acc1, v4); accum_bf4(acc1, v5);
            accum_bf4(acc1, v6); accum_bf4(acc1, v7);
        }
        for (; j < m; ++j) {
            int s = __shfl(idx, j);
            accum_bf4(acc0, gp[(size_t)s * 64 + lane]);
        }
    }
    float4 acc = f4add(acc0, acc1);

    float inv = inv_sqrt[node];
    float4 b4  = ((const float4*)bias)[lane];
    float4 ga4 = ((const float4*)gamma)[lane];
    float4 be4 = ((const float4*)beta)[lane];
    float4 m4  = ((const float4*)mean)[lane];
    float4 v4  = ((const float4*)var)[lane];
    float4 o;
    o.x = fmaxf((acc.x * inv + b4.x - m4.x) * (ga4.x * rsqrtf(v4.x + EPS)) + be4.x, 0.f);
    o.y = fmaxf((acc.y * inv + b4.y - m4.y) * (ga4.y * rsqrtf(v4.y + EPS)) + be4.y, 0.f);
    o.z = fmaxf((acc.z * inv + b4.z - m4.z) * (ga4.z * rsqrtf(v4.z + EPS)) + be4.z, 0.f);
    o.w = fmaxf((acc.w * inv + b4.w - m4.w) * (ga4.w * rsqrtf(v4.w + EPS)) + be4.w, 0.f);
    u16x4 oh;
    oh[0] = f2bf(o.x); oh[1] = f2bf(o.y); oh[2] = f2bf(o.z); oh[3] = f2bf(o.w);
    __builtin_nontemporal_store(oh, (u16x4*)out_hi + (size_t)node * 64 + lane);
    if (WRITE_LO) {
        u16x4 ol;
        ol[0] = f2bf(o.x - bf2f(oh[0]));
        ol[1] = f2bf(o.y - bf2f(oh[1]));
        ol[2] = f2bf(o.z - bf2f(oh[2]));
        ol[3] = f2bf(o.w - bf2f(oh[3]));
        __builtin_nontemporal_store(ol, (u16x4*)out_lo + (size_t)node * 64 + lane);
    }
}

// ---------------- final aggregation (C=40): fp32; all 64 lanes stay alive for shfl ----------------

__global__ __launch_bounds__(256) void agg_final_kernel(
        const float* __restrict__ g, const int* __restrict__ row_ptr,
        const int* __restrict__ srcs, const float* __restrict__ inv_sqrt,
        const float* __restrict__ bias, float* __restrict__ out, int n) {
    int node = (blockIdx.x << 2) + (threadIdx.x >> 6);
    int lane = threadIdx.x & 63;
    if (node >= n) return;
    int flane = (lane < CLS) ? lane : 0;       // clamped gather lane; store masked below
    float acc0 = g[(size_t)node * CLS + flane];
    float acc1 = 0.f;
    int beg = row_ptr[node];
    int cnt = row_ptr[node + 1] - beg;

    for (int base = 0; base < cnt; base += 64) {
        int m = cnt - base; if (m > 64) m = 64;
        int idx = (lane < m) ? srcs[beg + base + lane] : 0;
        int j = 0;
        for (; j + 8 <= m; j += 8) {
            int s0 = __shfl(idx, j + 0), s1 = __shfl(idx, j + 1);
            int s2 = __shfl(idx, j + 2), s3 = __shfl(idx, j + 3);
            int s4 = __shfl(idx, j + 4), s5 = __shfl(idx, j + 5);
            int s6 = __shfl(idx, j + 6), s7 = __shfl(idx, j + 7);
            float v0 = g[(size_t)s0 * CLS + flane];
            float v1 = g[(size_t)s1 * CLS + flane];
            float v2 = g[(size_t)s2 * CLS + flane];
            float v3 = g[(size_t)s3 * CLS + flane];
            float v4 = g[(size_t)s4 * CLS + flane];
            float v5 = g[(size_t)s5 * CLS + flane];
            float v6 = g[(size_t)s6 * CLS + flane];
            float v7 = g[(size_t)s7 * CLS + flane];
            acc0 += (v0 + v1) + (v2 + v3);
            acc1 += (v4 + v5) + (v6 + v7);
        }
        for (; j < m; ++j) {
            int s = __shfl(idx, j);
            acc0 += g[(size_t)s * CLS + flane];
        }
    }
    if (lane < CLS) {
        float r = (acc0 + acc1) * inv_sqrt[node] + bias[lane];
        __builtin_nontemporal_store(r, out + (size_t)node * CLS + lane);
    }
}

// ---------------- launch ----------------

extern "C" void kernel_launch(void* const* d_in, const int* in_sizes, int n_in,
                              void* d_out, int out_size, void* d_ws, size_t ws_size,
                              hipStream_t stream) {
    const float* x     = (const float*)d_in[0];
    const int*   edges = (const int*)d_in[1];
    const float* W1    = (const float*)d_in[2];
    const float* b1    = (const float*)d_in[3];
    const float* W2    = (const float*)d_in[4];
    const float* b2    = (const float*)d_in[5];
    const float* W3    = (const float*)d_in[6];
    const float* b3    = (const float*)d_in[7];
    const float* gamma = (const float*)d_in[8];
    const float* beta  = (const float*)d_in[9];
    const float* mean  = (const float*)d_in[10];
    const float* var   = (const float*)d_in[11];

    const int N = in_sizes[0] / FEAT;   // 50000
    const int E = in_sizes[1] / 2;      // 800000
    const int* src = edges;
    const int* dst = edges + E;

    char* ws = (char*)d_ws;
    auto alloc = [&](size_t bytes) -> char* {
        char* p = ws;
        ws += (bytes + 255) & ~(size_t)255;
        return p;
    };
    int*   counts     = (int*)  alloc((size_t)N * 4);
    int*   fillpos    = (int*)  alloc((size_t)N * 4);
    int*   row_ptr    = (int*)  alloc((size_t)(N + 1) * 4);
    int*   blocksums  = (int*)  alloc(256 * 4);
    float* inv_sqrt   = (float*)alloc((size_t)N * 4);
    int*   src_sorted = (int*)  alloc((size_t)E * 4);
    unsigned short* w1hi = (unsigned short*)alloc((size_t)FEAT * HID * 2);
    unsigned short* w1lo = (unsigned short*)alloc((size_t)FEAT * HID * 2);
    unsigned short* w2hi = (unsigned short*)alloc((size_t)HID * HID * 2);
    unsigned short* w2lo = (unsigned short*)alloc((size_t)HID * HID * 2);
    // g: bf16 for layers 1-2 (25.6 MB); reused as fp32 N*CLS (8 MB) for layer 3
    unsigned short* g    = (unsigned short*)alloc((size_t)N * HID * 2);
    unsigned short* h_hi = (unsigned short*)alloc((size_t)N * HID * 2); // 25.6 MB
    unsigned short* h_lo = (unsigned short*)alloc((size_t)N * HID * 2); // 25.6 MB
    // xbf (N*FEAT bf16 = 51.2 MB) aliases h_hi+h_lo: dead once GEMM1 completes,
    // and agg1 (first writer of h_hi) runs strictly after GEMM1 on the stream.
    unsigned short* xbf  = h_hi;

    int nb = (N + 255) / 256;           // 196
    int eb = (E + 255) / 256;

    // 1) fused prep: zero + W1/W2 split + x->bf16
    int prep_items = N + FEAT * HID + HID * HID + N * FEAT / 8;
    prep_cvt_kernel<<<(prep_items + 255) / 256, 256, 0, stream>>>(
        x, W1, W2, counts, fillpos, w1hi, w1lo, w2hi, w2lo, xbf, N);
    // 2-5) CSR build
    hist_kernel<<<eb, 256, 0, stream>>>(dst, counts, E);
    scan_block_kernel<<<nb, 256, 0, stream>>>(counts, row_ptr, blocksums, N);
    finalize_rowptr_kernel<<<nb, 256, 0, stream>>>(row_ptr, blocksums, counts, inv_sqrt, N, E, nb);
    fill_kernel<<<eb, 256, 0, stream>>>(src, dst, row_ptr, fillpos, src_sorted, E);

    dim3 pipe_grid((N + 255) / 256);    // 196 blocks, 256 rows x full 256 cols per block
    dim3 gemm3_grid((N + 63) / 64, 1);
    dim3 agg_grid((N + 3) / 4);

    // 6-7) layer 1: A = bf16(x), 256x256 depth-3 pipelined GEMM; agg1 -> h single bf16
    gemm_mfma_pipe_kernel<FEAT><<<pipe_grid, 512, 0, stream>>>(
        xbf, w1hi, w1lo, inv_sqrt, g, N);
    agg_bn_hl_kernel<false><<<agg_grid, 256, 0, stream>>>(g, row_ptr, src_sorted, inv_sqrt,
                                                          b1, gamma, beta, mean, var, h_hi, nullptr, N);
    // 8-9) layer 2: A = h1 single bf16; agg2 -> h2 hi/lo for fp32 GEMM3
    gemm_mfma_pipe_kernel<HID><<<pipe_grid, 512, 0, stream>>>(
        h_hi, w2hi, w2lo, inv_sqrt, g, N);
    agg_bn_hl_kernel<true><<<agg_grid, 256, 0, stream>>>(g, row_ptr, src_sorted, inv_sqrt,
                                                         b2, gamma, beta, mean, var, h_hi, h_lo, N);
    // 10-11) layer 3: fp32 vector GEMM reading hi/lo; fp32 g3 (reuses g buffer); fp32 final agg
    float* g3 = (float*)g;
    gemm_scaled_hl_kernel<<<gemm3_grid, 256, 0, stream>>>(h_hi, h_lo, W3, inv_sqrt, g3, N, HID, CLS);
    agg_final_kernel<<<agg_grid, 256, 0, stream>>>(g3, row_ptr, src_sorted, inv_sqrt,
                                                   b3, (float*)d_out, N);
}